// Round 1
// baseline (234.621 us; speedup 1.0000x reference)
//
#include <hip/hip_runtime.h>
#include <stdint.h>

// Problem constants
#define BATCH 32
#define LLEN  36864
#define CCH   16
#define DOUT  512
#define KW    24
#define LOUT  1536            // LLEN / KW
#define MROWS (BATCH * LOUT)  // 49152 windows
#define CK    384             // CCH * KW (inner dot length)
#define TWOK  48

typedef float fx4 __attribute__((ext_vector_type(4)));
typedef float f32x4 __attribute__((ext_vector_type(4)));
typedef __bf16 bf16x8 __attribute__((ext_vector_type(8)));

// ---------------------------------------------------------------------------
// K0: weight transposition.  w_off[o,c,k] -> woff_t[o][k*16+c]  (fp32)
//     w_def[d,c,k] -> wdef_t[d][k*16+c]  (bf16)
// Layout j = k*16+c matches the contiguous window layout of x.
// ---------------------------------------------------------------------------
__global__ __launch_bounds__(256) void prep_kernel(
    const float* __restrict__ w_off, const float* __restrict__ w_def,
    float* __restrict__ woff_t, __bf16* __restrict__ wdef_t)
{
    int idx = blockIdx.x * 256 + threadIdx.x;
    if (idx < TWOK * CK) {
        int o = idx / CK, rem = idx % CK;
        int k = rem >> 4, c = rem & 15;
        woff_t[idx] = w_off[o * CK + c * KW + k];
    }
    if (idx < DOUT * CK) {
        int d = idx / CK, rem = idx % CK;
        int k = rem >> 4, c = rem & 15;
        wdef_t[idx] = (__bf16)w_def[d * CK + c * KW + k];
    }
}

// ---------------------------------------------------------------------------
// K1: offsets + bilinear sampling.  One block = 128 windows.
// Phase 1: off[128x48] = win[128x384] . woff_t^T   (fp32, LDS-tiled, K-chunks of 64)
// Phase 2: per (w,k) compute sampling params; then write val[m][j] as bf16.
// ---------------------------------------------------------------------------
#define WB 128          // windows per block
#define KC 64           // K-chunk
#define WS 68           // winS/woffS padded stride (floats)

__global__ __launch_bounds__(256) void off_samp_kernel(
    const float* __restrict__ x, const float* __restrict__ woff_t,
    const float* __restrict__ b_off, __bf16* __restrict__ val)
{
    // Phase-overlapped LDS (61952 B total -> 2 blocks/CU)
    __shared__ char smem[61952];
    float* winS  = (float*)smem;             // [128][68] phase 1
    float* woffS = (float*)(smem + 34816);   // [48][68]  phase 1
    float* offS  = (float*)smem;             // [128][49] phase 2 (aliases winS)
    int*   i0S   = (int*)(smem + 25088);     // [24][128]
    float* w0S   = (float*)(smem + 37376);   // [24][128]
    float* w1S   = (float*)(smem + 49664);   // [24][128]

    const int t  = threadIdx.x;
    const int m0 = blockIdx.x * WB;          // block's first window (same batch: 1536%128==0)
    const int wg = t & 31;                   // thread's window group: w = wg + 32*u
    const int o0 = (t >> 5) * 6;             // 6 offsets per thread

    float acc[4][6];
#pragma unroll
    for (int u = 0; u < 4; ++u)
#pragma unroll
        for (int v = 0; v < 6; ++v) acc[u][v] = 0.f;

    for (int kt = 0; kt < CK; kt += KC) {
        __syncthreads();
        // stage win chunk: 128 x 64 floats (x rows ARE the windows, contiguous)
#pragma unroll
        for (int i = 0; i < 8; ++i) {
            int q = t + 256 * i;             // 2048 float4 total
            int row = q >> 4, c4 = q & 15;
            *(fx4*)&winS[row * WS + c4 * 4] =
                *(const fx4*)&x[(size_t)(m0 + row) * CK + kt + c4 * 4];
        }
        // stage woff chunk: 48 x 64 floats
#pragma unroll
        for (int i = 0; i < 3; ++i) {
            int q = t + 256 * i;             // 768 float4 total
            int row = q >> 4, c4 = q & 15;
            *(fx4*)&woffS[row * WS + c4 * 4] =
                *(const fx4*)&woff_t[row * CK + kt + c4 * 4];
        }
        __syncthreads();
        for (int jj = 0; jj < KC; jj += 4) {
            fx4 wv[4], of[6];
#pragma unroll
            for (int u = 0; u < 4; ++u)
                wv[u] = *(const fx4*)&winS[(wg + 32 * u) * WS + jj];
#pragma unroll
            for (int v = 0; v < 6; ++v)
                of[v] = *(const fx4*)&woffS[(o0 + v) * WS + jj];
#pragma unroll
            for (int u = 0; u < 4; ++u)
#pragma unroll
                for (int v = 0; v < 6; ++v)
                    acc[u][v] += wv[u].x * of[v].x + wv[u].y * of[v].y +
                                 wv[u].z * of[v].z + wv[u].w * of[v].w;
        }
    }
    __syncthreads();
    // write offsets (+bias) to LDS
    float boffv[6];
#pragma unroll
    for (int v = 0; v < 6; ++v) boffv[v] = b_off[o0 + v];
#pragma unroll
    for (int u = 0; u < 4; ++u)
#pragma unroll
        for (int v = 0; v < 6; ++v)
            offS[(wg + 32 * u) * 49 + o0 + v] = acc[u][v] + boffv[v];
    __syncthreads();

    // Phase 2a: sampling params per (window, k)
    const int b     = m0 / LOUT;
    const int lbase = m0 % LOUT;
#pragma unroll
    for (int i = 0; i < 12; ++i) {
        int q = t + 256 * i;                 // 3072 items
        int k = q >> 7, w = q & 127;
        float dy = offS[w * 49 + 2 * k];
        float dx = offS[w * 49 + 2 * k + 1];
        float wy = fmaxf(0.f, 1.f - fabsf(dy));
        float px = (float)((lbase + w) * KW + k) + dx;
        float x0f = floorf(px);
        float lw = px - x0f;
        int  i0 = (int)x0f;
        bool valid = (px > -1.0f) && (px < (float)LLEN);
        float w0v = (valid && i0 >= 0)          ? (1.f - lw) * wy : 0.f;
        float w1v = (valid && (i0 + 1) < LLEN)  ? lw * wy         : 0.f;
        int i0c = min(max(i0, 0), LLEN - 1);
        int i1c = min(max(i0 + 1, 0), LLEN - 1);
        i0S[k * 128 + w] = (int)((unsigned)i0c | ((unsigned)i1c << 16));
        w0S[k * 128 + w] = w0v;
        w1S[k * 128 + w] = w1v;
    }
    __syncthreads();

    // Phase 2b: gather + write val (bf16), coalesced in j
    const float* xb = x + (size_t)b * LLEN * CCH;
    __bf16* valb = val + (size_t)m0 * CK;
#pragma unroll 2
    for (int ww = 0; ww < 64; ++ww) {        // 2 windows per outer iter
        int base = ww * 768;
#pragma unroll
        for (int s = 0; s < 3; ++s) {
            int p = t + s * 256;             // 0..767
            int hi = (p >= CK) ? 1 : 0;
            int w2 = ww * 2 + hi;
            int j  = p - hi * CK;
            int k = j >> 4, c = j & 15;
            unsigned pk = (unsigned)i0S[k * 128 + w2];
            int i0c = (int)(pk & 0xffffu);
            int i1c = (int)(pk >> 16);
            float v = w0S[k * 128 + w2] * xb[i0c * CCH + c] +
                      w1S[k * 128 + w2] * xb[i1c * CCH + c];
            valb[base + p] = (__bf16)v;
        }
    }
}

// ---------------------------------------------------------------------------
// K2: out[M x 512] = val[M x 384] . wdef_t[512 x 384]^T + b_def
// m97-style: 128x128 tile, BK=64, global_load_lds width 16, mfma 16x16x32 bf16
// ---------------------------------------------------------------------------
#define BM 128
#define BN 128
#define BK 64

__device__ __forceinline__ void gload16(void* lds, const void* g)
{
    __builtin_amdgcn_global_load_lds(
        (const __attribute__((address_space(1))) uint32_t*)g,
        (__attribute__((address_space(3))) uint32_t*)lds, 16, 0, 0);
}

__global__ __launch_bounds__(256) void gemm_kernel(
    const __bf16* __restrict__ Aval, const __bf16* __restrict__ Bw,
    const float* __restrict__ bias, float* __restrict__ out)
{
    __shared__ __bf16 As[BM * BK];   // 16 KB
    __shared__ __bf16 Bs[BN * BK];   // 16 KB

    const int t = threadIdx.x;
    const int m0 = blockIdx.x * BM;
    const int n0 = blockIdx.y * BN;
    const int wave = t >> 6, lane = t & 63;
    const int wr = wave >> 1, wc = wave & 1;     // 2x2 wave grid, 64x64 each
    const int quad = lane >> 4, l16 = lane & 15;

    f32x4 acc[4][4];
#pragma unroll
    for (int i = 0; i < 4; ++i)
#pragma unroll
        for (int j = 0; j < 4; ++j) acc[i][j] = (f32x4){0.f, 0.f, 0.f, 0.f};

    const __bf16* Ag = Aval + (size_t)m0 * CK;
    const __bf16* Bg = Bw + (size_t)n0 * CK;

    for (int kt = 0; kt < CK; kt += BK) {
        __syncthreads();   // previous tile consumed
#pragma unroll
        for (int it = 0; it < 4; ++it) {
            int q = it * 256 + t;            // 1024 16B-chunks per tile
            int r = q >> 3, c8 = q & 7;      // row, col-of-8
            gload16(&As[q * 8], Ag + (size_t)r * CK + kt + c8 * 8);
            gload16(&Bs[q * 8], Bg + (size_t)r * CK + kt + c8 * 8);
        }
        __syncthreads();   // compiler drains vmcnt before barrier
#pragma unroll
        for (int ks = 0; ks < 2; ++ks) {
            bf16x8 af[4], bfr[4];
#pragma unroll
            for (int i = 0; i < 4; ++i) {
                int row = wr * 64 + i * 16 + l16;
                af[i] = *(const bf16x8*)&As[row * BK + ks * 32 + quad * 8];
                int col = wc * 64 + i * 16 + l16;
                bfr[i] = *(const bf16x8*)&Bs[col * BK + ks * 32 + quad * 8];
            }
#pragma unroll
            for (int i = 0; i < 4; ++i)
#pragma unroll
                for (int j = 0; j < 4; ++j)
                    acc[i][j] = __builtin_amdgcn_mfma_f32_16x16x32_bf16(
                        af[i], bfr[j], acc[i][j], 0, 0, 0);
        }
    }

    // epilogue: D[row=quad*4+r][col=l16] per verified gfx950 C/D layout
#pragma unroll
    for (int i = 0; i < 4; ++i) {
#pragma unroll
        for (int j = 0; j < 4; ++j) {
            int col = n0 + wc * 64 + j * 16 + l16;
            float bj = bias[col];
#pragma unroll
            for (int r = 0; r < 4; ++r) {
                int row = m0 + wr * 64 + i * 16 + quad * 4 + r;
                out[(size_t)row * DOUT + col] = acc[i][j][r] + bj;
            }
        }
    }
}

// ---------------------------------------------------------------------------
extern "C" void kernel_launch(void* const* d_in, const int* in_sizes, int n_in,
                              void* d_out, int out_size, void* d_ws, size_t ws_size,
                              hipStream_t stream)
{
    const float* x     = (const float*)d_in[0];
    const float* w_off = (const float*)d_in[1];
    const float* b_off = (const float*)d_in[2];
    const float* w_def = (const float*)d_in[3];
    const float* b_def = (const float*)d_in[4];
    float* out = (float*)d_out;

    char* ws = (char*)d_ws;
    __bf16* val    = (__bf16*)ws;                     // 37,748,736 B
    __bf16* wdef_t = (__bf16*)(ws + 37748736);        //    393,216 B
    float*  woff_t = (float*)(ws + 38141952);         //     73,728 B

    prep_kernel<<<768, 256, 0, stream>>>(w_off, w_def, woff_t, wdef_t);
    off_samp_kernel<<<MROWS / WB, 256, 0, stream>>>(x, woff_t, b_off, val);
    gemm_kernel<<<dim3(MROWS / BM, DOUT / BN), 256, 0, stream>>>(val, wdef_t, b_def, out);
}

// Round 2
// 226.200 us; speedup vs baseline: 1.0372x; 1.0372x over previous
//
#include <hip/hip_runtime.h>
#include <stdint.h>

// Problem constants
#define BATCH 32
#define LLEN  36864
#define CCH   16
#define DOUT  512
#define KW    24
#define LOUT  1536            // LLEN / KW
#define MROWS (BATCH * LOUT)  // 49152 windows
#define CK    384             // CCH * KW (inner dot length)
#define TWOK  48
#define NMK   (MROWS * KW)    // 1179648 (m,k) pairs

typedef float fx4 __attribute__((ext_vector_type(4)));
typedef float f32x4 __attribute__((ext_vector_type(4)));
typedef __bf16 bf16x8 __attribute__((ext_vector_type(8)));
typedef uint32_t u32x4 __attribute__((ext_vector_type(4)));

__device__ __forceinline__ void gload16(void* lds, const void* g)
{
    __builtin_amdgcn_global_load_lds(
        (const __attribute__((address_space(1))) uint32_t*)g,
        (__attribute__((address_space(3))) uint32_t*)lds, 16, 0, 0);
}

// ---------------------------------------------------------------------------
// K0: weight transposition to j = k*16+c layout (bf16).
// ---------------------------------------------------------------------------
__global__ __launch_bounds__(256) void prep_kernel(
    const float* __restrict__ w_off, const float* __restrict__ w_def,
    __bf16* __restrict__ woff_b, __bf16* __restrict__ wdef_b)
{
    int idx = blockIdx.x * 256 + threadIdx.x;
    if (idx < TWOK * CK) {
        int o = idx / CK, rem = idx % CK;
        int k = rem >> 4, c = rem & 15;
        woff_b[idx] = (__bf16)w_off[o * CK + c * KW + k];
    }
    if (idx < DOUT * CK) {
        int d = idx / CK, rem = idx % CK;
        int k = rem >> 4, c = rem & 15;
        wdef_b[idx] = (__bf16)w_def[d * CK + c * KW + k];
    }
}

// ---------------------------------------------------------------------------
// K1a: offset conv via MFMA.  Block = 64 windows (4 waves x 16 rows), N=48.
// A-frags read DIRECTLY from global x (fp32->bf16 in regs) -- no A LDS, no
// staging barriers.  woff (48x384 bf16) staged once in LDS, 392-elem padded
// stride (bank offset 4/row -> even spread).  Output: packed bf16 (dy,dx)
// with bias added.
// ---------------------------------------------------------------------------
__global__ __launch_bounds__(256, 3) void offsets_kernel(
    const float* __restrict__ x, const __bf16* __restrict__ woff_b,
    const float* __restrict__ b_off, uint32_t* __restrict__ dxy)
{
    __shared__ __bf16 Bs[TWOK * 392];    // 37632 B
    __shared__ float  offS[64 * 49];     // 12544 B   (total 50176 -> 3 blk/CU)

    const int t = threadIdx.x;
    // stage woff: 2304 16B-chunks, 9 per thread
#pragma unroll
    for (int i = 0; i < 9; ++i) {
        int ch = t + 256 * i;            // 0..2303
        int row = ch / 48, cc = ch % 48;
        *(u32x4*)&Bs[row * 392 + cc * 8] =
            *(const u32x4*)&woff_b[row * CK + cc * 8];
    }
    __syncthreads();

    const int wave = t >> 6, lane = t & 63;
    const int quad = lane >> 4, l16 = lane & 15;
    const int m0 = blockIdx.x * 64;
    const int row = m0 + wave * 16 + l16;
    const float* xr = x + (size_t)row * CK;

    f32x4 acc[3] = {};
#pragma unroll
    for (int ks = 0; ks < 12; ++ks) {
        int k0 = ks * 32 + quad * 8;
        fx4 a0 = *(const fx4*)&xr[k0];
        fx4 a1 = *(const fx4*)&xr[k0 + 4];
        bf16x8 af;
        af[0] = (__bf16)a0.x; af[1] = (__bf16)a0.y;
        af[2] = (__bf16)a0.z; af[3] = (__bf16)a0.w;
        af[4] = (__bf16)a1.x; af[5] = (__bf16)a1.y;
        af[6] = (__bf16)a1.z; af[7] = (__bf16)a1.w;
#pragma unroll
        for (int j = 0; j < 3; ++j) {
            bf16x8 bf = *(const bf16x8*)&Bs[(j * 16 + l16) * 392 + k0];
            acc[j] = __builtin_amdgcn_mfma_f32_16x16x32_bf16(af, bf, acc[j], 0, 0, 0);
        }
    }
    // D[row=quad*4+r][col=j*16+l16] -> LDS
#pragma unroll
    for (int j = 0; j < 3; ++j)
#pragma unroll
        for (int r = 0; r < 4; ++r)
            offS[(wave * 16 + quad * 4 + r) * 49 + j * 16 + l16] = acc[j][r];
    __syncthreads();

    // pack (dy,dx)+bias -> global, coalesced: gidx = m0*24 + id
#pragma unroll
    for (int s = 0; s < 6; ++s) {
        int id = t + 256 * s;            // 0..1535 == r*24+k
        int r = id / 24, k = id - r * 24;
        float dy = offS[r * 49 + 2 * k]     + b_off[2 * k];
        float dx = offS[r * 49 + 2 * k + 1] + b_off[2 * k + 1];
        union { __bf16 h[2]; uint32_t u; } p;
        p.h[0] = (__bf16)dy; p.h[1] = (__bf16)dx;
        dxy[(size_t)m0 * KW + id] = p.u;
    }
}

// ---------------------------------------------------------------------------
// K1b: bilinear gather.  Thread per (m,k): 16 channels -> 32B bf16 store.
// No LDS, no barriers; pure stream.  x is L3-resident after K1a.
// ---------------------------------------------------------------------------
__global__ __launch_bounds__(256) void gather_kernel(
    const float* __restrict__ x, const uint32_t* __restrict__ dxy,
    __bf16* __restrict__ val)
{
    int id = blockIdx.x * 256 + threadIdx.x;      // 0..NMK
    int b = id / (LOUT * KW);                     // batch
    int pos = id - b * (LOUT * KW);               // l*24+k in [0,36864)

    union { uint32_t u; __bf16 h[2]; } p;
    p.u = dxy[id];
    float dy = (float)p.h[0], dx = (float)p.h[1];

    float wy  = fmaxf(0.f, 1.f - fabsf(dy));
    float px  = (float)pos + dx;
    float x0f = floorf(px);
    float lw  = px - x0f;
    int   i0  = (int)x0f;
    bool valid = (px > -1.0f) && (px < (float)LLEN);
    float w0 = (valid && i0 >= 0)         ? (1.f - lw) * wy : 0.f;
    float w1 = (valid && (i0 + 1) < LLEN) ? lw * wy         : 0.f;
    int i0c = min(max(i0, 0), LLEN - 1);
    int i1c = min(max(i0 + 1, 0), LLEN - 1);

    const float* xb = x + (size_t)b * LLEN * CCH;
    const fx4* p0 = (const fx4*)&xb[(size_t)i0c * CCH];
    const fx4* p1 = (const fx4*)&xb[(size_t)i1c * CCH];

    bf16x8 o0, o1;
#pragma unroll
    for (int q = 0; q < 2; ++q) {
        fx4 v0 = p0[q], v1 = p1[q];
        o0[q * 4 + 0] = (__bf16)(w0 * v0.x + w1 * v1.x);
        o0[q * 4 + 1] = (__bf16)(w0 * v0.y + w1 * v1.y);
        o0[q * 4 + 2] = (__bf16)(w0 * v0.z + w1 * v1.z);
        o0[q * 4 + 3] = (__bf16)(w0 * v0.w + w1 * v1.w);
    }
#pragma unroll
    for (int q = 0; q < 2; ++q) {
        fx4 v0 = p0[q + 2], v1 = p1[q + 2];
        o1[q * 4 + 0] = (__bf16)(w0 * v0.x + w1 * v1.x);
        o1[q * 4 + 1] = (__bf16)(w0 * v0.y + w1 * v1.y);
        o1[q * 4 + 2] = (__bf16)(w0 * v0.z + w1 * v1.z);
        o1[q * 4 + 3] = (__bf16)(w0 * v0.w + w1 * v1.w);
    }
    __bf16* vp = val + (size_t)id * 16;
    *(bf16x8*)vp       = o0;
    *(bf16x8*)(vp + 8) = o1;
}

// ---------------------------------------------------------------------------
// K2: out[M x 512] = val . wdef^T + bias.  128x256 tile, 512 thr (8 waves,
// 2x4 grid of 64x64), BK=64, source-permuted global_load_lds + XOR-swizzled
// ds_read_b128 (chunk p of row r holds global chunk p^(r&7)) -> no bank
// pileups while keeping the lane-linear LDS dest the DMA requires.
// ---------------------------------------------------------------------------
#define BM 128
#define BN 256
#define BK 64

__global__ __launch_bounds__(512, 4) void gemm_kernel(
    const __bf16* __restrict__ A, const __bf16* __restrict__ Bw,
    const float* __restrict__ bias, float* __restrict__ out)
{
    __shared__ __bf16 As[BM * BK];   // 16 KB
    __shared__ __bf16 Bs[BN * BK];   // 32 KB

    const int t = threadIdx.x;
    const int m0 = blockIdx.x * BM;
    const int n0 = blockIdx.y * BN;
    const int wave = t >> 6, lane = t & 63;
    const int quad = lane >> 4, l16 = lane & 15;
    const int wr = wave >> 2, wc = wave & 3;     // 2x4 waves of 64x64

    f32x4 acc[4][4] = {};
    const __bf16* Ag = A + (size_t)m0 * CK;
    const __bf16* Bg = Bw + (size_t)n0 * CK;

    for (int kt = 0; kt < CK; kt += BK) {
        __syncthreads();
#pragma unroll
        for (int it = 0; it < 2; ++it) {         // As: 1024 chunks
            int q = it * 512 + t;
            int r = q >> 3, c8 = q & 7;
            int sc = c8 ^ (r & 7);
            gload16(&As[q * 8], Ag + (size_t)r * CK + kt + sc * 8);
        }
#pragma unroll
        for (int it = 0; it < 4; ++it) {         // Bs: 2048 chunks
            int q = it * 512 + t;
            int r = q >> 3, c8 = q & 7;
            int sc = c8 ^ (r & 7);
            gload16(&Bs[q * 8], Bg + (size_t)r * CK + kt + sc * 8);
        }
        __syncthreads();
#pragma unroll
        for (int ks = 0; ks < 2; ++ks) {
            bf16x8 af[4], bfr[4];
#pragma unroll
            for (int i = 0; i < 4; ++i) {
                int row = wr * 64 + i * 16 + l16;
                af[i] = *(const bf16x8*)&As[row * BK + (((ks * 4 + quad) ^ (row & 7)) * 8)];
                int col = wc * 64 + i * 16 + l16;
                bfr[i] = *(const bf16x8*)&Bs[col * BK + (((ks * 4 + quad) ^ (col & 7)) * 8)];
            }
#pragma unroll
            for (int i = 0; i < 4; ++i)
#pragma unroll
                for (int j = 0; j < 4; ++j)
                    acc[i][j] = __builtin_amdgcn_mfma_f32_16x16x32_bf16(
                        af[i], bfr[j], acc[i][j], 0, 0, 0);
        }
    }

    // epilogue: D[row=quad*4+r][col=l16]
#pragma unroll
    for (int j = 0; j < 4; ++j) {
        int col = n0 + wc * 64 + j * 16 + l16;
        float bj = bias[col];
#pragma unroll
        for (int i = 0; i < 4; ++i) {
            int rowb = m0 + wr * 64 + i * 16 + quad * 4;
#pragma unroll
            for (int r = 0; r < 4; ++r)
                out[(size_t)(rowb + r) * DOUT + col] = acc[i][j][r] + bj;
        }
    }
}

// ---------------------------------------------------------------------------
extern "C" void kernel_launch(void* const* d_in, const int* in_sizes, int n_in,
                              void* d_out, int out_size, void* d_ws, size_t ws_size,
                              hipStream_t stream)
{
    const float* x     = (const float*)d_in[0];
    const float* w_off = (const float*)d_in[1];
    const float* b_off = (const float*)d_in[2];
    const float* w_def = (const float*)d_in[3];
    const float* b_def = (const float*)d_in[4];
    float* out = (float*)d_out;

    char* ws = (char*)d_ws;
    __bf16*   val    = (__bf16*)ws;                   // 37,748,736 B
    __bf16*   wdef_b = (__bf16*)(ws + 37748736);      //    393,216 B
    __bf16*   woff_b = (__bf16*)(ws + 38141952);      //     36,864 B
    uint32_t* dxy    = (uint32_t*)(ws + 38178816);    //  4,718,592 B  (tot ~42.9 MB)

    prep_kernel<<<768, 256, 0, stream>>>(w_off, w_def, woff_b, wdef_b);
    offsets_kernel<<<MROWS / 64, 256, 0, stream>>>(x, woff_b, b_off, dxy);
    gather_kernel<<<NMK / 256, 256, 0, stream>>>(x, dxy, val);
    gemm_kernel<<<dim3(MROWS / BM, DOUT / BN), 512, 0, stream>>>(val, wdef_b, b_def, out);
}

// Round 3
// 212.200 us; speedup vs baseline: 1.1057x; 1.0660x over previous
//
#include <hip/hip_runtime.h>
#include <stdint.h>

// Problem constants
#define BATCH 32
#define LLEN  36864
#define CCH   16
#define DOUT  512
#define KW    24
#define LOUT  1536            // LLEN / KW
#define MROWS (BATCH * LOUT)  // 49152 windows
#define CK    384             // CCH * KW (inner dot length)
#define TWOK  48

typedef float fx4 __attribute__((ext_vector_type(4)));
typedef float f32x4 __attribute__((ext_vector_type(4)));
typedef __bf16 bf16x8 __attribute__((ext_vector_type(8)));
typedef uint32_t u32x4 __attribute__((ext_vector_type(4)));

__device__ __forceinline__ void gload16(void* lds, const void* g)
{
    __builtin_amdgcn_global_load_lds(
        (const __attribute__((address_space(1))) uint32_t*)g,
        (__attribute__((address_space(3))) uint32_t*)lds, 16, 0, 0);
}

// ---------------------------------------------------------------------------
// K0: weight transposition to j = k*16+c layout (bf16).
// ---------------------------------------------------------------------------
__global__ __launch_bounds__(256) void prep_kernel(
    const float* __restrict__ w_off, const float* __restrict__ w_def,
    __bf16* __restrict__ woff_b, __bf16* __restrict__ wdef_b)
{
    int idx = blockIdx.x * 256 + threadIdx.x;
    if (idx < TWOK * CK) {
        int o = idx / CK, rem = idx % CK;
        int k = rem >> 4, c = rem & 15;
        woff_b[idx] = (__bf16)w_off[o * CK + c * KW + k];
    }
    if (idx < DOUT * CK) {
        int d = idx / CK, rem = idx % CK;
        int k = rem >> 4, c = rem & 15;
        wdef_b[idx] = (__bf16)w_def[d * CK + c * KW + k];
    }
}

// ---------------------------------------------------------------------------
// K1: offset conv via MFMA.  Block = 64 windows (4 waves x 16 rows), N=48.
// A-frags read DIRECTLY from global x (fp32->bf16 in regs).  Output: packed
// bf16 (dy,dx) with bias added.
// ---------------------------------------------------------------------------
__global__ __launch_bounds__(256, 3) void offsets_kernel(
    const float* __restrict__ x, const __bf16* __restrict__ woff_b,
    const float* __restrict__ b_off, uint32_t* __restrict__ dxy)
{
    __shared__ __bf16 Bs[TWOK * 392];    // 37632 B
    __shared__ float  offS[64 * 49];     // 12544 B   (total 50176 -> 3 blk/CU)

    const int t = threadIdx.x;
#pragma unroll
    for (int i = 0; i < 9; ++i) {
        int ch = t + 256 * i;            // 0..2303
        int row = ch / 48, cc = ch % 48;
        *(u32x4*)&Bs[row * 392 + cc * 8] =
            *(const u32x4*)&woff_b[row * CK + cc * 8];
    }
    __syncthreads();

    const int wave = t >> 6, lane = t & 63;
    const int quad = lane >> 4, l16 = lane & 15;
    const int m0 = blockIdx.x * 64;
    const int row = m0 + wave * 16 + l16;
    const float* xr = x + (size_t)row * CK;

    f32x4 acc[3] = {};
#pragma unroll
    for (int ks = 0; ks < 12; ++ks) {
        int k0 = ks * 32 + quad * 8;
        fx4 a0 = *(const fx4*)&xr[k0];
        fx4 a1 = *(const fx4*)&xr[k0 + 4];
        bf16x8 af;
        af[0] = (__bf16)a0.x; af[1] = (__bf16)a0.y;
        af[2] = (__bf16)a0.z; af[3] = (__bf16)a0.w;
        af[4] = (__bf16)a1.x; af[5] = (__bf16)a1.y;
        af[6] = (__bf16)a1.z; af[7] = (__bf16)a1.w;
#pragma unroll
        for (int j = 0; j < 3; ++j) {
            bf16x8 bf = *(const bf16x8*)&Bs[(j * 16 + l16) * 392 + k0];
            acc[j] = __builtin_amdgcn_mfma_f32_16x16x32_bf16(af, bf, acc[j], 0, 0, 0);
        }
    }
#pragma unroll
    for (int j = 0; j < 3; ++j)
#pragma unroll
        for (int r = 0; r < 4; ++r)
            offS[(wave * 16 + quad * 4 + r) * 49 + j * 16 + l16] = acc[j][r];
    __syncthreads();

#pragma unroll
    for (int s = 0; s < 6; ++s) {
        int id = t + 256 * s;            // 0..1535 == r*24+k
        int r = id / 24, k = id - r * 24;
        float dy = offS[r * 49 + 2 * k]     + b_off[2 * k];
        float dx = offS[r * 49 + 2 * k + 1] + b_off[2 * k + 1];
        union { __bf16 h[2]; uint32_t u; } p;
        p.h[0] = (__bf16)dy; p.h[1] = (__bf16)dx;
        dxy[(size_t)m0 * KW + id] = p.u;
    }
}

// ---------------------------------------------------------------------------
// K2: fused gather + GEMM.  out[M x 512] = gather(x, dxy) . wdef^T + bias.
// 64x256 tile, 256 thr (1x4 waves of 64x64), BK=64.
// A-tile: each thread owns one (m,k) pair per chunk -- loads dxy + two x-rows
// from L2/L3, bilinear-combines, ds_writes 32B into XOR-chunk-swizzled As.
// Next chunk's gather loads are issued AFTER the second barrier so they fly
// under the MFMA phase (classic prefetch-past-barrier).
// B-tile: global_load_lds w16 with source-permuted XOR swizzle (DMA needs
// lane-linear dest; As doesn't since it's VALU-written).
// ---------------------------------------------------------------------------
#define BM 64
#define BN 256
#define BK 64

__global__ __launch_bounds__(256) void gemm_fused(
    const float* __restrict__ x, const uint32_t* __restrict__ dxy,
    const __bf16* __restrict__ Bw, const float* __restrict__ bias,
    float* __restrict__ out)
{
    __shared__ __bf16 As[BM * BK];   //  8 KB
    __shared__ __bf16 Bs[BN * BK];   // 32 KB

    const int t = threadIdx.x;
    const int m0 = blockIdx.x * BM;
    const int n0 = blockIdx.y * BN;
    const int wave = t >> 6, lane = t & 63;
    const int quad = lane >> 4, l16 = lane & 15;

    // this thread's gather pair: window row mloc, kernel slot k4 (+4/chunk)
    const int mloc = t >> 2, k4 = t & 3;
    const int Mrow = m0 + mloc;
    const int b    = Mrow / LOUT;
    const int lb   = Mrow - b * LOUT;
    const float* xb = x + (size_t)b * LLEN * CCH;

    f32x4 acc[4][4] = {};
    const __bf16* Bg = Bw + (size_t)n0 * CK;

    fx4 g0[4], g1[4];
    float w0, w1;

    auto load_pair = [&](int kk) {
        union { uint32_t u; __bf16 h[2]; } p;
        p.u = dxy[(size_t)Mrow * KW + kk];
        float dy = (float)p.h[0], dx = (float)p.h[1];
        float wy  = fmaxf(0.f, 1.f - fabsf(dy));
        float px  = (float)(lb * KW + kk) + dx;
        float x0f = floorf(px);
        float lw  = px - x0f;
        int   i0  = (int)x0f;
        bool valid = (px > -1.0f) && (px < (float)LLEN);
        w0 = (valid && i0 >= 0)         ? (1.f - lw) * wy : 0.f;
        w1 = (valid && (i0 + 1) < LLEN) ? lw * wy         : 0.f;
        int i0c = min(max(i0, 0), LLEN - 1);
        int i1c = min(max(i0 + 1, 0), LLEN - 1);
        const fx4* p0 = (const fx4*)&xb[(size_t)i0c * CCH];
        const fx4* p1 = (const fx4*)&xb[(size_t)i1c * CCH];
#pragma unroll
        for (int q = 0; q < 4; ++q) { g0[q] = p0[q]; g1[q] = p1[q]; }
    };

    load_pair(k4);    // chunk 0

    for (int kt = 0; kt < CK; kt += BK) {
        __syncthreads();                     // prev tile consumed
        // pack current pair -> As (two 16B chunks, XOR-swizzled)
        bf16x8 oa, ob;
#pragma unroll
        for (int q = 0; q < 2; ++q) {
            fx4 v0 = g0[q], v1 = g1[q];
            oa[q * 4 + 0] = (__bf16)(w0 * v0.x + w1 * v1.x);
            oa[q * 4 + 1] = (__bf16)(w0 * v0.y + w1 * v1.y);
            oa[q * 4 + 2] = (__bf16)(w0 * v0.z + w1 * v1.z);
            oa[q * 4 + 3] = (__bf16)(w0 * v0.w + w1 * v1.w);
        }
#pragma unroll
        for (int q = 0; q < 2; ++q) {
            fx4 v0 = g0[q + 2], v1 = g1[q + 2];
            ob[q * 4 + 0] = (__bf16)(w0 * v0.x + w1 * v1.x);
            ob[q * 4 + 1] = (__bf16)(w0 * v0.y + w1 * v1.y);
            ob[q * 4 + 2] = (__bf16)(w0 * v0.z + w1 * v1.z);
            ob[q * 4 + 3] = (__bf16)(w0 * v0.w + w1 * v1.w);
        }
        int g = 2 * k4;
        *(bf16x8*)&As[mloc * BK + ((g ^ (mloc & 7)) * 8)]       = oa;
        *(bf16x8*)&As[mloc * BK + (((g + 1) ^ (mloc & 7)) * 8)] = ob;
        // stage B via DMA: 2048 chunks / 256 thr
#pragma unroll
        for (int it = 0; it < 8; ++it) {
            int q = it * 256 + t;
            int r = q >> 3, c8 = q & 7;
            int sc = c8 ^ (r & 7);
            gload16(&Bs[q * 8], Bg + (size_t)r * CK + kt + sc * 8);
        }
        __syncthreads();                     // drains Bs DMA (+lds writes)
        // prefetch next chunk's gather under the MFMA phase
        if (kt + BK < CK) load_pair((kt >> 4) + 4 + k4);
        // MFMA: wave covers rows 0..63, cols wave*64..+63
#pragma unroll
        for (int ks = 0; ks < 2; ++ks) {
            bf16x8 af[4], bfr[4];
#pragma unroll
            for (int i = 0; i < 4; ++i) {
                int row = i * 16 + l16;
                af[i] = *(const bf16x8*)&As[row * BK + (((ks * 4 + quad) ^ (row & 7)) * 8)];
                int col = wave * 64 + i * 16 + l16;
                bfr[i] = *(const bf16x8*)&Bs[col * BK + (((ks * 4 + quad) ^ (col & 7)) * 8)];
            }
#pragma unroll
            for (int i = 0; i < 4; ++i)
#pragma unroll
                for (int j = 0; j < 4; ++j)
                    acc[i][j] = __builtin_amdgcn_mfma_f32_16x16x32_bf16(
                        af[i], bfr[j], acc[i][j], 0, 0, 0);
        }
    }

    // epilogue: D[row=quad*4+r][col=l16]
#pragma unroll
    for (int j = 0; j < 4; ++j) {
        int col = n0 + wave * 64 + j * 16 + l16;
        float bj = bias[col];
#pragma unroll
        for (int i = 0; i < 4; ++i) {
            int rowb = m0 + i * 16 + quad * 4;
#pragma unroll
            for (int r = 0; r < 4; ++r)
                out[(size_t)(rowb + r) * DOUT + col] = acc[i][j][r] + bj;
        }
    }
}

// ---------------------------------------------------------------------------
extern "C" void kernel_launch(void* const* d_in, const int* in_sizes, int n_in,
                              void* d_out, int out_size, void* d_ws, size_t ws_size,
                              hipStream_t stream)
{
    const float* x     = (const float*)d_in[0];
    const float* w_off = (const float*)d_in[1];
    const float* b_off = (const float*)d_in[2];
    const float* w_def = (const float*)d_in[3];
    const float* b_def = (const float*)d_in[4];
    float* out = (float*)d_out;

    char* ws = (char*)d_ws;
    uint32_t* dxy    = (uint32_t*)ws;                 // 4,718,592 B
    __bf16*   wdef_b = (__bf16*)(ws + 4718592);       //   393,216 B
    __bf16*   woff_b = (__bf16*)(ws + 5111808);       //    36,864 B  (tot ~5.1 MB)

    prep_kernel<<<768, 256, 0, stream>>>(w_off, w_def, woff_b, wdef_b);
    offsets_kernel<<<MROWS / 64, 256, 0, stream>>>(x, woff_b, b_off, dxy);
    gemm_fused<<<dim3(MROWS / BM, DOUT / BN), 256, 0, stream>>>(x, dxy, wdef_b, b_def, out);
}

// Round 4
// 206.726 us; speedup vs baseline: 1.1349x; 1.0265x over previous
//
#include <hip/hip_runtime.h>
#include <stdint.h>

// Problem constants
#define BATCH 32
#define LLEN  36864
#define CCH   16
#define DOUT  512
#define KW    24
#define LOUT  1536            // LLEN / KW
#define MROWS (BATCH * LOUT)  // 49152 windows
#define CK    384             // CCH * KW (inner dot length)
#define TWOK  48

typedef float fx4 __attribute__((ext_vector_type(4)));
typedef float f32x4 __attribute__((ext_vector_type(4)));
typedef __bf16 bf16x8 __attribute__((ext_vector_type(8)));
typedef uint32_t u32x4 __attribute__((ext_vector_type(4)));

__device__ __forceinline__ void gload16(void* lds, const void* g)
{
    __builtin_amdgcn_global_load_lds(
        (const __attribute__((address_space(1))) uint32_t*)g,
        (__attribute__((address_space(3))) uint32_t*)lds, 16, 0, 0);
}

// ---------------------------------------------------------------------------
// K0: weight transposition to j = k*16+c layout (bf16).
// ---------------------------------------------------------------------------
__global__ __launch_bounds__(256) void prep_kernel(
    const float* __restrict__ w_off, const float* __restrict__ w_def,
    __bf16* __restrict__ woff_b, __bf16* __restrict__ wdef_b)
{
    int idx = blockIdx.x * 256 + threadIdx.x;
    if (idx < TWOK * CK) {
        int o = idx / CK, rem = idx % CK;
        int k = rem >> 4, c = rem & 15;
        woff_b[idx] = (__bf16)w_off[o * CK + c * KW + k];
    }
    if (idx < DOUT * CK) {
        int d = idx / CK, rem = idx % CK;
        int k = rem >> 4, c = rem & 15;
        wdef_b[idx] = (__bf16)w_def[d * CK + c * KW + k];
    }
}

// ---------------------------------------------------------------------------
// K1: offset conv via MFMA.  Block = 64 windows (4 waves x 16 rows), N=48.
// A-frags read DIRECTLY from global x (fp32->bf16 in regs).  Output: packed
// bf16 (dy,dx) with bias added.
// ---------------------------------------------------------------------------
__global__ __launch_bounds__(256, 3) void offsets_kernel(
    const float* __restrict__ x, const __bf16* __restrict__ woff_b,
    const float* __restrict__ b_off, uint32_t* __restrict__ dxy)
{
    __shared__ __bf16 Bs[TWOK * 392];    // 37632 B
    __shared__ float  offS[64 * 49];     // 12544 B   (total 50176 -> 3 blk/CU)

    const int t = threadIdx.x;
#pragma unroll
    for (int i = 0; i < 9; ++i) {
        int ch = t + 256 * i;            // 0..2303
        int row = ch / 48, cc = ch % 48;
        *(u32x4*)&Bs[row * 392 + cc * 8] =
            *(const u32x4*)&woff_b[row * CK + cc * 8];
    }
    __syncthreads();

    const int wave = t >> 6, lane = t & 63;
    const int quad = lane >> 4, l16 = lane & 15;
    const int m0 = blockIdx.x * 64;
    const int row = m0 + wave * 16 + l16;
    const float* xr = x + (size_t)row * CK;

    f32x4 acc[3] = {};
#pragma unroll
    for (int ks = 0; ks < 12; ++ks) {
        int k0 = ks * 32 + quad * 8;
        fx4 a0 = *(const fx4*)&xr[k0];
        fx4 a1 = *(const fx4*)&xr[k0 + 4];
        bf16x8 af;
        af[0] = (__bf16)a0.x; af[1] = (__bf16)a0.y;
        af[2] = (__bf16)a0.z; af[3] = (__bf16)a0.w;
        af[4] = (__bf16)a1.x; af[5] = (__bf16)a1.y;
        af[6] = (__bf16)a1.z; af[7] = (__bf16)a1.w;
#pragma unroll
        for (int j = 0; j < 3; ++j) {
            bf16x8 bf = *(const bf16x8*)&Bs[(j * 16 + l16) * 392 + k0];
            acc[j] = __builtin_amdgcn_mfma_f32_16x16x32_bf16(af, bf, acc[j], 0, 0, 0);
        }
    }
#pragma unroll
    for (int j = 0; j < 3; ++j)
#pragma unroll
        for (int r = 0; r < 4; ++r)
            offS[(wave * 16 + quad * 4 + r) * 49 + j * 16 + l16] = acc[j][r];
    __syncthreads();

#pragma unroll
    for (int s = 0; s < 6; ++s) {
        int id = t + 256 * s;            // 0..1535 == r*24+k
        int r = id / 24, k = id - r * 24;
        float dy = offS[r * 49 + 2 * k]     + b_off[2 * k];
        float dx = offS[r * 49 + 2 * k + 1] + b_off[2 * k + 1];
        union { __bf16 h[2]; uint32_t u; } p;
        p.h[0] = (__bf16)dy; p.h[1] = (__bf16)dx;
        dxy[(size_t)m0 * KW + id] = p.u;
    }
}

// ---------------------------------------------------------------------------
// K2: fused gather + GEMM, FULL output width per block.
// out[128 x 512] per block = gather(x, dxy)[128x384] . wdef^T + bias.
// BN=512 means each (m,k) pair is gathered exactly ONCE (R3 did it twice),
// and B is staged once per m-block (147 MB L2 total vs 295 MB).
// 512 thr = 8 waves in 2x4 grid; wave tile 64x128 (acc[4][8]).
// A-tile: thread owns one (m,k) pair/chunk: dxy + two x-rows -> bilinear ->
// 32B ds_write into XOR-chunk-swizzled As; next chunk's loads prefetched
// after the second barrier to fly under MFMA.
// B-tile: global_load_lds w16, source-permuted XOR swizzle.
// LDS: As 16 KB + Bs 64 KB = 80 KB (gfx950 allows >64 KB/workgroup).
// ---------------------------------------------------------------------------
#define BM 128
#define BN 512
#define BK 64

__global__ __launch_bounds__(512, 2) void gemm_fused(
    const float* __restrict__ x, const uint32_t* __restrict__ dxy,
    const __bf16* __restrict__ Bw, const float* __restrict__ bias,
    float* __restrict__ out)
{
    __shared__ __bf16 As[BM * BK];   // 16 KB
    __shared__ __bf16 Bs[BN * BK];   // 64 KB

    const int t = threadIdx.x;
    const int m0 = blockIdx.x * BM;
    const int wave = t >> 6, lane = t & 63;
    const int quad = lane >> 4, l16 = lane & 15;
    const int wr = wave >> 2, wc = wave & 3;     // 2x4 waves of 64x128

    // this thread's gather pair: window row mloc, kernel slot k4 (+4/chunk)
    const int mloc = t >> 2, k4 = t & 3;
    const int Mrow = m0 + mloc;
    const int b    = Mrow / LOUT;
    const int lb   = Mrow - b * LOUT;
    const float* xb = x + (size_t)b * LLEN * CCH;

    f32x4 acc[4][8] = {};

    fx4 g0[4], g1[4];
    float w0, w1;

    auto load_pair = [&](int kk) {
        union { uint32_t u; __bf16 h[2]; } p;
        p.u = dxy[(size_t)Mrow * KW + kk];
        float dy = (float)p.h[0], dx = (float)p.h[1];
        float wy  = fmaxf(0.f, 1.f - fabsf(dy));
        float px  = (float)(lb * KW + kk) + dx;
        float x0f = floorf(px);
        float lw  = px - x0f;
        int   i0  = (int)x0f;
        bool valid = (px > -1.0f) && (px < (float)LLEN);
        w0 = (valid && i0 >= 0)         ? (1.f - lw) * wy : 0.f;
        w1 = (valid && (i0 + 1) < LLEN) ? lw * wy         : 0.f;
        int i0c = min(max(i0, 0), LLEN - 1);
        int i1c = min(max(i0 + 1, 0), LLEN - 1);
        const fx4* p0 = (const fx4*)&xb[(size_t)i0c * CCH];
        const fx4* p1 = (const fx4*)&xb[(size_t)i1c * CCH];
#pragma unroll
        for (int q = 0; q < 4; ++q) { g0[q] = p0[q]; g1[q] = p1[q]; }
    };

    load_pair(k4);    // chunk 0

    for (int kt = 0; kt < CK; kt += BK) {
        __syncthreads();                     // prev tile consumed
        // pack current pair -> As (two 16B chunks, XOR-swizzled)
        bf16x8 oa, ob;
#pragma unroll
        for (int q = 0; q < 2; ++q) {
            fx4 v0 = g0[q], v1 = g1[q];
            oa[q * 4 + 0] = (__bf16)(w0 * v0.x + w1 * v1.x);
            oa[q * 4 + 1] = (__bf16)(w0 * v0.y + w1 * v1.y);
            oa[q * 4 + 2] = (__bf16)(w0 * v0.z + w1 * v1.z);
            oa[q * 4 + 3] = (__bf16)(w0 * v0.w + w1 * v1.w);
        }
#pragma unroll
        for (int q = 0; q < 2; ++q) {
            fx4 v0 = g0[q + 2], v1 = g1[q + 2];
            ob[q * 4 + 0] = (__bf16)(w0 * v0.x + w1 * v1.x);
            ob[q * 4 + 1] = (__bf16)(w0 * v0.y + w1 * v1.y);
            ob[q * 4 + 2] = (__bf16)(w0 * v0.z + w1 * v1.z);
            ob[q * 4 + 3] = (__bf16)(w0 * v0.w + w1 * v1.w);
        }
        int g = 2 * k4;
        *(bf16x8*)&As[mloc * BK + ((g ^ (mloc & 7)) * 8)]       = oa;
        *(bf16x8*)&As[mloc * BK + (((g + 1) ^ (mloc & 7)) * 8)] = ob;
        // stage B via DMA: 4096 chunks / 512 thr (full 512-col width)
#pragma unroll
        for (int it = 0; it < 8; ++it) {
            int q = it * 512 + t;
            int r = q >> 3, c8 = q & 7;
            int sc = c8 ^ (r & 7);
            gload16(&Bs[q * 8], Bw + (size_t)r * CK + kt + sc * 8);
        }
        __syncthreads();                     // drains Bs DMA (+lds writes)
        // prefetch next chunk's gather under the MFMA phase
        if (kt + BK < CK) load_pair((kt >> 4) + 4 + k4);
        // MFMA: wave tile 64x128 at (wr*64, wc*128)
#pragma unroll
        for (int ks = 0; ks < 2; ++ks) {
            bf16x8 af[4], bfr[8];
#pragma unroll
            for (int i = 0; i < 4; ++i) {
                int row = wr * 64 + i * 16 + l16;
                af[i] = *(const bf16x8*)&As[row * BK + (((ks * 4 + quad) ^ (row & 7)) * 8)];
            }
#pragma unroll
            for (int j = 0; j < 8; ++j) {
                int col = wc * 128 + j * 16 + l16;
                bfr[j] = *(const bf16x8*)&Bs[col * BK + (((ks * 4 + quad) ^ (col & 7)) * 8)];
            }
#pragma unroll
            for (int i = 0; i < 4; ++i)
#pragma unroll
                for (int j = 0; j < 8; ++j)
                    acc[i][j] = __builtin_amdgcn_mfma_f32_16x16x32_bf16(
                        af[i], bfr[j], acc[i][j], 0, 0, 0);
        }
    }

    // epilogue: D[row=quad*4+r][col=l16]
#pragma unroll
    for (int j = 0; j < 8; ++j) {
        int col = wc * 128 + j * 16 + l16;
        float bj = bias[col];
#pragma unroll
        for (int i = 0; i < 4; ++i) {
            int rowb = m0 + wr * 64 + i * 16 + quad * 4;
#pragma unroll
            for (int r = 0; r < 4; ++r)
                out[(size_t)(rowb + r) * DOUT + col] = acc[i][j][r] + bj;
        }
    }
}

// ---------------------------------------------------------------------------
extern "C" void kernel_launch(void* const* d_in, const int* in_sizes, int n_in,
                              void* d_out, int out_size, void* d_ws, size_t ws_size,
                              hipStream_t stream)
{
    const float* x     = (const float*)d_in[0];
    const float* w_off = (const float*)d_in[1];
    const float* b_off = (const float*)d_in[2];
    const float* w_def = (const float*)d_in[3];
    const float* b_def = (const float*)d_in[4];
    float* out = (float*)d_out;

    char* ws = (char*)d_ws;
    uint32_t* dxy    = (uint32_t*)ws;                 // 4,718,592 B
    __bf16*   wdef_b = (__bf16*)(ws + 4718592);       //   393,216 B
    __bf16*   woff_b = (__bf16*)(ws + 5111808);       //    36,864 B  (tot ~5.1 MB)

    prep_kernel<<<768, 256, 0, stream>>>(w_off, w_def, woff_b, wdef_b);
    offsets_kernel<<<MROWS / 64, 256, 0, stream>>>(x, woff_b, b_off, dxy);
    gemm_fused<<<MROWS / BM, 512, 0, stream>>>(x, dxy, wdef_b, b_def, out);
}

// Round 5
// 196.556 us; speedup vs baseline: 1.1937x; 1.0517x over previous
//
#include <hip/hip_runtime.h>
#include <stdint.h>

// Problem constants
#define BATCH 32
#define LLEN  36864
#define CCH   16
#define DOUT  512
#define KW    24
#define LOUT  1536            // LLEN / KW
#define MROWS (BATCH * LOUT)  // 49152 windows
#define CK    384             // CCH * KW (inner dot length)
#define TWOK  48

typedef float fx4 __attribute__((ext_vector_type(4)));
typedef float f32x4 __attribute__((ext_vector_type(4)));
typedef __bf16 bf16x8 __attribute__((ext_vector_type(8)));
typedef uint32_t u32x4 __attribute__((ext_vector_type(4)));

__device__ __forceinline__ void gload16(void* lds, const void* g)
{
    __builtin_amdgcn_global_load_lds(
        (const __attribute__((address_space(1))) uint32_t*)g,
        (__attribute__((address_space(3))) uint32_t*)lds, 16, 0, 0);
}

// ---------------------------------------------------------------------------
// K0: weight transposition to j = k*16+c layout (bf16).
// ---------------------------------------------------------------------------
__global__ __launch_bounds__(256) void prep_kernel(
    const float* __restrict__ w_off, const float* __restrict__ w_def,
    __bf16* __restrict__ woff_b, __bf16* __restrict__ wdef_b)
{
    int idx = blockIdx.x * 256 + threadIdx.x;
    if (idx < TWOK * CK) {
        int o = idx / CK, rem = idx % CK;
        int k = rem >> 4, c = rem & 15;
        woff_b[idx] = (__bf16)w_off[o * CK + c * KW + k];
    }
    if (idx < DOUT * CK) {
        int d = idx / CK, rem = idx % CK;
        int k = rem >> 4, c = rem & 15;
        wdef_b[idx] = (__bf16)w_def[d * CK + c * KW + k];
    }
}

// ---------------------------------------------------------------------------
// K1: fully fused offsets + gather + GEMM.
// Block = 96 windows x full 512 output cols.  Grid = 512 blocks = exactly
// 2 per CU (balanced; R4's 384 blocks @1/CU ran at 75% utilization).
// Prologue: woff staged to LDS (Bs area); waves 0-5 compute off[96x48] via
//   MFMA with A-frags direct from global x; bias-added offsets -> LDS;
//   each gather thread packs its 6 (dy,dx) bf16 pairs into registers.
// K-loop (unrolled x6): thread (t<384) gathers one (m,k) pair/chunk from
//   L2-warm x, ds_writes 32B into XOR-swizzled As; B DMA'd via
//   global_load_lds w16 source-permuted; next gather prefetched after the
//   second barrier to fly under 48 MFMAs (8 waves, wave tile 48x128).
// LDS: As 12 KB + Bs 64 KB (prologue aliases woff/offS into Bs) = 76 KB.
// ---------------------------------------------------------------------------
#define BM 96
#define BN 512
#define BK 64

__global__ __launch_bounds__(512) void gemm_fused(
    const float* __restrict__ x, const __bf16* __restrict__ woff_b,
    const float* __restrict__ b_off, const __bf16* __restrict__ Bw,
    const float* __restrict__ bias, float* __restrict__ out)
{
    __shared__ __bf16 As[BM * BK];       // 12 KB
    __shared__ char  smemB[BN * BK * 2]; // 64 KB
    __bf16* Bs    = (__bf16*)smemB;
    __bf16* WoffS = (__bf16*)smemB;                 // [48][392] prologue
    float*  offS  = (float*)(smemB + 38144);        // [96][49]  prologue

    const int t = threadIdx.x;
    const int m0 = blockIdx.x * BM;
    const int wave = t >> 6, lane = t & 63;
    const int quad = lane >> 4, l16 = lane & 15;
    const int wr = wave >> 2, wc = wave & 3;        // 2x4 waves: tile 48x128

    // gather ownership (threads 0..383): row mloc, k-slot k4 (+4 per chunk)
    const int mloc = t >> 2, k4 = t & 3;
    const int Mrow = m0 + mloc;
    const int b    = m0 / LOUT;                     // 1536 % 96 == 0
    const int lb   = Mrow - b * LOUT;
    const float* xb = x + (size_t)b * LLEN * CCH;

    // ---- prologue: stage woff ----
#pragma unroll
    for (int i = 0; i < 5; ++i) {
        int q = t + 512 * i;                        // 2304 16B chunks
        if (q < 2304) {
            int row = q / 48, cc = q - row * 48;
            *(u32x4*)&WoffS[row * 392 + cc * 8] =
                *(const u32x4*)&woff_b[row * CK + cc * 8];
        }
    }
    __syncthreads();

    // ---- prologue: offsets MFMA (waves 0..5 cover 96 rows) ----
    if (wave < 6) {
        const float* xr = x + (size_t)(m0 + wave * 16 + l16) * CK;
        f32x4 oacc[3] = {};
#pragma unroll
        for (int ks = 0; ks < 12; ++ks) {
            int k0 = ks * 32 + quad * 8;
            fx4 a0 = *(const fx4*)&xr[k0];
            fx4 a1 = *(const fx4*)&xr[k0 + 4];
            bf16x8 af;
            af[0] = (__bf16)a0.x; af[1] = (__bf16)a0.y;
            af[2] = (__bf16)a0.z; af[3] = (__bf16)a0.w;
            af[4] = (__bf16)a1.x; af[5] = (__bf16)a1.y;
            af[6] = (__bf16)a1.z; af[7] = (__bf16)a1.w;
#pragma unroll
            for (int j = 0; j < 3; ++j) {
                bf16x8 bf = *(const bf16x8*)&WoffS[(j * 16 + l16) * 392 + k0];
                oacc[j] = __builtin_amdgcn_mfma_f32_16x16x32_bf16(af, bf, oacc[j], 0, 0, 0);
            }
        }
        float bo[3];
#pragma unroll
        for (int j = 0; j < 3; ++j) bo[j] = b_off[j * 16 + l16];
#pragma unroll
        for (int j = 0; j < 3; ++j)
#pragma unroll
            for (int r = 0; r < 4; ++r)
                offS[(wave * 16 + quad * 4 + r) * 49 + j * 16 + l16] = oacc[j][r] + bo[j];
    }
    __syncthreads();

    // ---- prologue: pack this thread's 6 (dy,dx) pairs into regs ----
    uint32_t dxyr[6];
    if (t < 4 * BM) {
#pragma unroll
        for (int cc = 0; cc < 6; ++cc) {
            int kk = 4 * cc + k4;
            float dy = offS[mloc * 49 + 2 * kk];
            float dx = offS[mloc * 49 + 2 * kk + 1];
            union { __bf16 h[2]; uint32_t u; } p;
            p.h[0] = (__bf16)dy; p.h[1] = (__bf16)dx;
            dxyr[cc] = p.u;
        }
    }

    f32x4 acc[3][8] = {};
    fx4 g0[4], g1[4];
    float w0, w1;

    auto load_pair = [&](uint32_t pk, int kk) {
        union { uint32_t u; __bf16 h[2]; } p; p.u = pk;
        float dy = (float)p.h[0], dx = (float)p.h[1];
        float wy  = fmaxf(0.f, 1.f - fabsf(dy));
        float px  = (float)(lb * KW + kk) + dx;
        float x0f = floorf(px);
        float lw  = px - x0f;
        int   i0  = (int)x0f;
        bool valid = (px > -1.0f) && (px < (float)LLEN);
        w0 = (valid && i0 >= 0)         ? (1.f - lw) * wy : 0.f;
        w1 = (valid && (i0 + 1) < LLEN) ? lw * wy         : 0.f;
        int i0c = min(max(i0, 0), LLEN - 1);
        int i1c = min(max(i0 + 1, 0), LLEN - 1);
        const fx4* p0 = (const fx4*)&xb[(size_t)i0c * CCH];
        const fx4* p1 = (const fx4*)&xb[(size_t)i1c * CCH];
#pragma unroll
        for (int q = 0; q < 4; ++q) { g0[q] = p0[q]; g1[q] = p1[q]; }
    };

    if (t < 4 * BM) load_pair(dxyr[0], k4);

#pragma unroll
    for (int cc = 0; cc < 6; ++cc) {
        const int kt = cc * BK;
        __syncthreads();                 // prev tile consumed / prologue LDS free
        if (t < 4 * BM) {
            bf16x8 oa, ob;
#pragma unroll
            for (int q = 0; q < 2; ++q) {
                fx4 v0 = g0[q], v1 = g1[q];
                oa[q * 4 + 0] = (__bf16)(w0 * v0.x + w1 * v1.x);
                oa[q * 4 + 1] = (__bf16)(w0 * v0.y + w1 * v1.y);
                oa[q * 4 + 2] = (__bf16)(w0 * v0.z + w1 * v1.z);
                oa[q * 4 + 3] = (__bf16)(w0 * v0.w + w1 * v1.w);
            }
#pragma unroll
            for (int q = 0; q < 2; ++q) {
                fx4 v0 = g0[q + 2], v1 = g1[q + 2];
                ob[q * 4 + 0] = (__bf16)(w0 * v0.x + w1 * v1.x);
                ob[q * 4 + 1] = (__bf16)(w0 * v0.y + w1 * v1.y);
                ob[q * 4 + 2] = (__bf16)(w0 * v0.z + w1 * v1.z);
                ob[q * 4 + 3] = (__bf16)(w0 * v0.w + w1 * v1.w);
            }
            int g = 2 * k4;
            *(bf16x8*)&As[mloc * BK + ((g ^ (mloc & 7)) * 8)]       = oa;
            *(bf16x8*)&As[mloc * BK + (((g + 1) ^ (mloc & 7)) * 8)] = ob;
        }
        // stage B via DMA: 4096 chunks / 512 thr
#pragma unroll
        for (int it = 0; it < 8; ++it) {
            int q = it * 512 + t;
            int r = q >> 3, c8 = q & 7;
            int sc = c8 ^ (r & 7);
            gload16(&Bs[q * 8], Bw + (size_t)r * CK + kt + sc * 8);
        }
        __syncthreads();                 // drains Bs DMA + As writes
        if (cc + 1 < 6 && t < 4 * BM)    // prefetch under MFMA
            load_pair(dxyr[cc + 1], 4 * (cc + 1) + k4);
#pragma unroll
        for (int ks = 0; ks < 2; ++ks) {
            bf16x8 af[3], bfr[8];
#pragma unroll
            for (int i = 0; i < 3; ++i) {
                int row = wr * 48 + i * 16 + l16;
                af[i] = *(const bf16x8*)&As[row * BK + (((ks * 4 + quad) ^ (row & 7)) * 8)];
            }
#pragma unroll
            for (int j = 0; j < 8; ++j) {
                int col = wc * 128 + j * 16 + l16;
                bfr[j] = *(const bf16x8*)&Bs[col * BK + (((ks * 4 + quad) ^ (col & 7)) * 8)];
            }
#pragma unroll
            for (int i = 0; i < 3; ++i)
#pragma unroll
                for (int j = 0; j < 8; ++j)
                    acc[i][j] = __builtin_amdgcn_mfma_f32_16x16x32_bf16(
                        af[i], bfr[j], acc[i][j], 0, 0, 0);
        }
    }

    // epilogue: D[row=quad*4+r][col=l16]
#pragma unroll
    for (int j = 0; j < 8; ++j) {
        int col = wc * 128 + j * 16 + l16;
        float bj = bias[col];
#pragma unroll
        for (int i = 0; i < 3; ++i) {
            int rowb = m0 + wr * 48 + i * 16 + quad * 4;
#pragma unroll
            for (int r = 0; r < 4; ++r)
                out[(size_t)(rowb + r) * DOUT + col] = acc[i][j][r] + bj;
        }
    }
}

// ---------------------------------------------------------------------------
extern "C" void kernel_launch(void* const* d_in, const int* in_sizes, int n_in,
                              void* d_out, int out_size, void* d_ws, size_t ws_size,
                              hipStream_t stream)
{
    const float* x     = (const float*)d_in[0];
    const float* w_off = (const float*)d_in[1];
    const float* b_off = (const float*)d_in[2];
    const float* w_def = (const float*)d_in[3];
    const float* b_def = (const float*)d_in[4];
    float* out = (float*)d_out;

    char* ws = (char*)d_ws;
    __bf16* wdef_b = (__bf16*)ws;                 // 393,216 B
    __bf16* woff_b = (__bf16*)(ws + 393216);      //  36,864 B

    prep_kernel<<<768, 256, 0, stream>>>(w_off, w_def, woff_b, wdef_b);
    gemm_fused<<<MROWS / BM, 512, 0, stream>>>(x, woff_b, b_off, wdef_b, b_def, out);
}